// Round 2
// baseline (800.463 us; speedup 1.0000x reference)
//
#include <hip/hip_runtime.h>
#include <hip/hip_bf16.h>

#define N_ATOMS 50000
#define N_PAIRS 800000
#define N_EMB   128
#define N_DIST  100
#define N_HID   128
#define TP      128   // pairs per block (8 waves x 16 rows)

typedef __attribute__((ext_vector_type(8))) short bf16x8;
typedef __attribute__((ext_vector_type(4))) float f32x4;

__device__ __forceinline__ short f2b(float x) {
  union { float f; unsigned u; } v; v.f = x;
  unsigned r = (v.u + 0x7FFF + ((v.u >> 16) & 1)) >> 16;   // RNE
  return (short)r;
}
__device__ __forceinline__ float b2f(short b) {
  union { unsigned u; float f; } v; v.u = ((unsigned)(unsigned short)b) << 16;
  return v.f;
}
__device__ __forceinline__ float fast_tanh(float x) {
  // tanh(x) = 1 - 2/(exp2(x*2*log2e)+1); exact at +-inf, ~1e-6 abs error
  const float z = __builtin_amdgcn_exp2f(x * 2.8853900817779268f);
  return 1.f - 2.f * __builtin_amdgcn_rcpf(z + 1.f);
}

// fragment-order index for B operand of mfma_f32_16x16x32_bf16:
// [kstep][ntile][lane=quad*16+n15][j], element (k,n): quad=(k>>3)&3, j=k&7
__device__ __forceinline__ int frag_idx(int k, int n) {
  return ((((k >> 5) * 8 + (n >> 4)) * 64) + (((k >> 3) & 3) * 16) + (n & 15)) * 8 + (k & 7);
}

// async 16B global -> LDS (wave-uniform base + lane*16 pattern)
__device__ __forceinline__ void g2lds16(const void* g, void* l) {
  __builtin_amdgcn_global_load_lds(
      (const __attribute__((address_space(1))) unsigned*)g,
      (__attribute__((address_space(3))) unsigned*)l, 16, 0, 0);
}
// stage 32KB of pre-formatted weights (16384 shorts) with 512 threads
__device__ __forceinline__ void stage_weights(const short* __restrict__ src,
                                              short* WS, int tid) {
  #pragma unroll
  for (int r = 0; r < 4; ++r) {
    const int off = (r * 512 + tid) * 8;   // 8 shorts = 16B per issue
    g2lds16(src + off, WS + off);
  }
}

// ------------- kernel 0: format weights to bf16 fragment order (once) -------
__global__ __launch_bounds__(256) void prep_kernel(
    const float* __restrict__ Wcf, const float* __restrict__ Wdf,
    const float* __restrict__ Wfc, short* __restrict__ Wcf_f,
    short* __restrict__ Wdf_f, short* __restrict__ Wfc_f) {
  const int e = blockIdx.x * 256 + threadIdx.x;   // 16384 total
  const int k = e >> 7, n = e & 127;
  const int fi = frag_idx(k, n);
  Wcf_f[fi] = f2b(Wcf[k * N_HID + n]);
  Wfc_f[fi] = f2b(Wfc[k * N_EMB + n]);
  Wdf_f[fi] = (k < N_DIST) ? f2b(Wdf[k * N_HID + n]) : (short)0;
}

// --- kernel 1 (fused): afh = af@Wcf + bcf; out = af - tanh((bdf*afh)@Wfc) ---
// Replaces old afh_kernel + out_kernel: afh tile stays on-chip between the
// two GEMMs (saves a 25.6MB re-read + one dispatch + the agg memset).
__global__ __launch_bounds__(512) void afh_out_kernel(
    const float* __restrict__ af, const short* __restrict__ Wcf_f,
    const short* __restrict__ Wfc_f, const float* __restrict__ bcf,
    const float* __restrict__ bdf, float* __restrict__ afh,
    float* __restrict__ out) {
  __shared__ short WS[128 * 128];   // 32KB weights (Wcf then Wfc)
  __shared__ short HS[128 * 128];   // 32KB bdf*afh (bf16, xor-swizzled)
  const int tid = threadIdx.x;
  const int lane = tid & 63, w = tid >> 6;
  const int lane15 = lane & 15, quad = lane >> 4;
  const int a0 = blockIdx.x * 128;

  stage_weights(Wcf_f, WS, tid);

  f32x4 acc[8];
  #pragma unroll
  for (int nt = 0; nt < 8; ++nt) {
    const float b = bcf[nt * 16 + lane15];
    acc[nt] = (f32x4){b, b, b, b};
  }
  const int arow = min(a0 + w * 16 + lane15, N_ATOMS - 1);
  const float* __restrict__ p = af + (long)arow * N_EMB;
  __syncthreads();                                  // WS = Wcf staged

  for (int ks = 0; ks < 4; ++ks) {
    const int k0 = ks * 32 + quad * 8;
    const float4 x = *(const float4*)(p + k0);
    const float4 y = *(const float4*)(p + k0 + 4);
    bf16x8 a;
    a[0] = f2b(x.x); a[1] = f2b(x.y); a[2] = f2b(x.z); a[3] = f2b(x.w);
    a[4] = f2b(y.x); a[5] = f2b(y.y); a[6] = f2b(y.z); a[7] = f2b(y.w);
    #pragma unroll
    for (int nt = 0; nt < 8; ++nt) {
      const bf16x8 b = *(const bf16x8*)&WS[((ks * 8 + nt) * 64 + lane) * 8];
      acc[nt] = __builtin_amdgcn_mfma_f32_16x16x32_bf16(a, b, acc[nt], 0, 0, 0);
    }
  }
  __syncthreads();                                  // all waves done reading Wcf

  stage_weights(Wfc_f, WS, tid);                    // async; overlaps below

  // write afh + build HS = bdf * afh (wave-local rows, swizzled)
  #pragma unroll
  for (int reg = 0; reg < 4; ++reg) {
    const int lr = w * 16 + quad * 4 + reg;         // local row 0..127
    const int row = a0 + lr;
    #pragma unroll
    for (int nt = 0; nt < 8; ++nt) {
      const int col = nt * 16 + lane15;
      const float v = acc[nt][reg];
      if (row < N_ATOMS) afh[(long)row * N_HID + col] = v;
      const int ch = (col >> 3) ^ (lr & 15);
      HS[(lr << 7) + (ch << 3) + (col & 7)] = f2b(v * bdf[col]);
    }
  }
  __syncthreads();                                  // Wfc staged (HS wave-local)

  // second GEMM: tanh((bdf*afh) @ Wfc)
  f32x4 acc2[8];
  #pragma unroll
  for (int nt = 0; nt < 8; ++nt) acc2[nt] = (f32x4){0.f, 0.f, 0.f, 0.f};
  const int m = w * 16 + lane15;                    // local A-row
  #pragma unroll
  for (int ks = 0; ks < 4; ++ks) {
    const int ch = (ks * 4 + quad) ^ lane15;        // (m & 15) == lane15
    const bf16x8 a = *(const bf16x8*)&HS[(m << 7) + (ch << 3)];
    #pragma unroll
    for (int nt = 0; nt < 8; ++nt) {
      const bf16x8 b = *(const bf16x8*)&WS[((ks * 8 + nt) * 64 + lane) * 8];
      acc2[nt] = __builtin_amdgcn_mfma_f32_16x16x32_bf16(a, b, acc2[nt], 0, 0, 0);
    }
  }
  #pragma unroll
  for (int reg = 0; reg < 4; ++reg) {
    const int row = a0 + w * 16 + quad * 4 + reg;
    if (row < N_ATOMS) {
      #pragma unroll
      for (int nt = 0; nt < 8; ++nt) {
        const size_t idx = (size_t)row * N_EMB + nt * 16 + lane15;
        out[idx] = af[idx] - fast_tanh(acc2[nt][reg]);   // pair adds agg later
      }
    }
  }
}

// -------- kernel 2: fused MFMA per-pair dh -> h -> tanh(h@Wfc) -> seg-agg ----
// Barrier-free: weights read directly from global (L1/L2-resident, coalesced
// 1KB/wave per fragment), HS is wave-local only -> no __syncthreads at all.
// LDS 64KB -> 32KB (more blocks/CU). XCD-bijective swizzle keeps sorted-mi
// atomic targets within one XCD's L2 (kills the 147MB write bounce).
__global__ __launch_bounds__(512, 6) void pair_kernel(
    const float* __restrict__ dist, const int* __restrict__ mi,
    const int* __restrict__ mj, const short* __restrict__ Wdf_f,
    const short* __restrict__ Wfc_f, const float* __restrict__ bdf,
    const float* __restrict__ afh, float* __restrict__ out) {
  __shared__ short HS[TP * 128];    // 32KB: h then msg (bf16), xor-swizzled

  const int tid = threadIdx.x;
  const int lane = tid & 63;
  const int w = tid >> 6;           // wave 0..7 -> rows [16w,16w+16)
  const int lane15 = lane & 15;
  const int quad = lane >> 4;
  const int R = w * 16;

  // XCD-bijective swizzle (m204 form): contiguous pair-chunks per XCD
  const int nwg = gridDim.x;
  const int q = nwg >> 3, rr8 = nwg & 7;
  const int xcd = blockIdx.x & 7, slot = blockIdx.x >> 3;
  const int wg = (xcd < rr8 ? xcd * (q + 1) : rr8 * (q + 1) + (xcd - rr8) * q) + slot;
  const long pbase = (long)wg * TP;

  // ---- prefetch full dist row -> bf16 A-fragments ----
  const float* __restrict__ drow = dist + (pbase + R + lane15) * (long)N_DIST;
  bf16x8 afr[4];
  {
    float4 x[4], y[3];
    #pragma unroll
    for (int ks = 0; ks < 3; ++ks) {               // k0+7 <= 95 < 100
      const int k0 = ks * 32 + quad * 8;
      x[ks] = *(const float4*)(drow + k0);
      y[ks] = *(const float4*)(drow + k0 + 4);
    }
    const float4 z = {0.f, 0.f, 0.f, 0.f};
    x[3] = (quad == 0) ? *(const float4*)(drow + 96) : z;  // k 96..99
    #pragma unroll
    for (int ks = 0; ks < 3; ++ks) {
      afr[ks][0] = f2b(x[ks].x); afr[ks][1] = f2b(x[ks].y);
      afr[ks][2] = f2b(x[ks].z); afr[ks][3] = f2b(x[ks].w);
      afr[ks][4] = f2b(y[ks].x); afr[ks][5] = f2b(y[ks].y);
      afr[ks][6] = f2b(y[ks].z); afr[ks][7] = f2b(y[ks].w);
    }
    afr[3][0] = f2b(x[3].x); afr[3][1] = f2b(x[3].y);
    afr[3][2] = f2b(x[3].z); afr[3][3] = f2b(x[3].w);
    afr[3][4] = 0; afr[3][5] = 0; afr[3][6] = 0; afr[3][7] = 0;
  }

  f32x4 acc[8];
  #pragma unroll
  for (int nt = 0; nt < 8; ++nt) {
    const float b = bdf[nt * 16 + lane15];
    acc[nt] = (f32x4){b, b, b, b};
  }

  // ---- phase A: dh[16x128] = dist_tile @ Wdf + bdf (B-frags from global) ----
  __builtin_amdgcn_s_setprio(1);
  #pragma unroll
  for (int ks = 0; ks < 4; ++ks) {
    #pragma unroll
    for (int nt = 0; nt < 8; ++nt) {
      const bf16x8 b = *(const bf16x8*)&Wdf_f[((ks * 8 + nt) * 64 + lane) * 8];
      acc[nt] = __builtin_amdgcn_mfma_f32_16x16x32_bf16(afr[ks], b, acc[nt], 0, 0, 0);
    }
  }
  __builtin_amdgcn_s_setprio(0);

  // ---- phase B: h = dh * afh[mj[p]], bf16 -> HS (own rows; swizzled) ----
  #pragma unroll
  for (int reg = 0; reg < 4; ++reg) {
    const int r = R + quad * 4 + reg;               // C-layout row
    const long j = mj[pbase + r];                   // uniform per 16 lanes
    const float* __restrict__ arow = afh + j * N_HID + lane15;
    float g[8];
    #pragma unroll
    for (int nt = 0; nt < 8; ++nt) g[nt] = arow[nt * 16];  // 64B-coalesced
    #pragma unroll
    for (int nt = 0; nt < 8; ++nt) {
      const int col = nt * 16 + lane15;
      const float h = acc[nt][reg] * g[nt];
      const int ch = (col >> 3) ^ (r & 15);
      HS[(r << 7) + (ch << 3) + (col & 7)] = f2b(h);
    }
  }
  // HS traffic is wave-internal (same-wave DS ops are in-order); compiler fence
  __builtin_amdgcn_wave_barrier();

  // ---- phase C: msg[16x128] = h @ Wfc (B-frags from global) ----
  f32x4 acc2[8];
  #pragma unroll
  for (int nt = 0; nt < 8; ++nt) acc2[nt] = (f32x4){0.f, 0.f, 0.f, 0.f};
  const int m = R + lane15;                         // A-layout row
  __builtin_amdgcn_s_setprio(1);
  #pragma unroll
  for (int ks = 0; ks < 4; ++ks) {
    const int ch = (ks * 4 + quad) ^ lane15;        // (m & 15) == lane15
    const bf16x8 a = *(const bf16x8*)&HS[(m << 7) + (ch << 3)];  // 2-way max
    #pragma unroll
    for (int nt = 0; nt < 8; ++nt) {
      const bf16x8 b = *(const bf16x8*)&Wfc_f[((ks * 8 + nt) * 64 + lane) * 8];
      acc2[nt] = __builtin_amdgcn_mfma_f32_16x16x32_bf16(a, b, acc2[nt], 0, 0, 0);
    }
  }
  __builtin_amdgcn_s_setprio(0);

  // ---- epilogue: tanh -> HS as msg (own rows only) ----
  #pragma unroll
  for (int reg = 0; reg < 4; ++reg) {
    const int r = R + quad * 4 + reg;
    #pragma unroll
    for (int nt = 0; nt < 8; ++nt) {
      const int col = nt * 16 + lane15;
      const float tv = fast_tanh(acc2[nt][reg]);
      const int ch = (col >> 3) ^ (r & 15);
      HS[(r << 7) + (ch << 3) + (col & 7)] = f2b(tv);
    }
  }
  __builtin_amdgcn_wave_barrier();

  // ---- per-wave segmented reduction over sorted mi (16 rows, 2 cols/lane) ----
  {
    const int c0 = lane * 2;                        // cols c0, c0+1 (adjacent)
    const long p0 = pbase + R;
    float s0 = 0.f, s1 = 0.f;
    int cur = mi[p0];                               // wave-uniform value
    for (int rr = 0; rr < 16; ++rr) {
      const int r = R + rr;
      const int idx = mi[p0 + rr];                  // wave-uniform value
      if (idx != cur) {                             // uniform branch at runtime
        atomicAdd(&out[(size_t)cur * N_EMB + c0], s0);
        atomicAdd(&out[(size_t)cur * N_EMB + c0 + 1], s1);
        s0 = s1 = 0.f; cur = idx;
      }
      const int ch = (c0 >> 3) ^ (r & 15);          // c0,c0+1 share chunk
      const unsigned v =
          *(const unsigned*)&HS[(r << 7) + (ch << 3) + (c0 & 7)];  // 2-way, free
      s0 += b2f((short)(v & 0xFFFF));
      s1 += b2f((short)(v >> 16));
    }
    atomicAdd(&out[(size_t)cur * N_EMB + c0], s0);
    atomicAdd(&out[(size_t)cur * N_EMB + c0 + 1], s1);
  }
}

extern "C" void kernel_launch(void* const* d_in, const int* in_sizes, int n_in,
                              void* d_out, int out_size, void* d_ws, size_t ws_size,
                              hipStream_t stream) {
  const float* af   = (const float*)d_in[0];
  const float* dist = (const float*)d_in[1];
  const int*   mi   = (const int*)d_in[3];
  const int*   mj   = (const int*)d_in[4];
  const float* Wcf  = (const float*)d_in[5];
  const float* Wdf  = (const float*)d_in[6];
  const float* Wfc  = (const float*)d_in[7];
  const float* bcf  = (const float*)d_in[8];
  const float* bdf  = (const float*)d_in[9];
  float* out = (float*)d_out;

  float* afh = (float*)d_ws;                        // 25.6 MB
  short* Wcf_f = (short*)(afh + (size_t)N_ATOMS * N_HID);  // 3 x 32KB, frag order
  short* Wdf_f = Wcf_f + 128 * 128;
  short* Wfc_f = Wdf_f + 128 * 128;

  prep_kernel<<<64, 256, 0, stream>>>(Wcf, Wdf, Wfc, Wcf_f, Wdf_f, Wfc_f);
  afh_out_kernel<<<(N_ATOMS + 127) / 128, 512, 0, stream>>>(
      af, Wcf_f, Wfc_f, bcf, bdf, afh, out);
  pair_kernel<<<N_PAIRS / TP, 512, 0, stream>>>(
      dist, mi, mj, Wdf_f, Wfc_f, bdf, afh, out);
}

// Round 3
// 608.632 us; speedup vs baseline: 1.3152x; 1.3152x over previous
//
#include <hip/hip_runtime.h>
#include <hip/hip_bf16.h>

#define N_ATOMS 50000
#define N_PAIRS 800000
#define N_EMB   128
#define N_DIST  100
#define N_HID   128
#define NB      250   // persistent pair blocks
#define SPW     25    // strips (16 pairs) per wave; 250*8*25*16 = 800000

typedef __attribute__((ext_vector_type(8))) short bf16x8;
typedef __attribute__((ext_vector_type(4))) float f32x4;

__device__ __forceinline__ short f2b(float x) {
  union { float f; unsigned u; } v; v.f = x;
  unsigned r = (v.u + 0x7FFF + ((v.u >> 16) & 1)) >> 16;   // RNE
  return (short)r;
}
__device__ __forceinline__ float b2f(short b) {
  union { unsigned u; float f; } v; v.u = ((unsigned)(unsigned short)b) << 16;
  return v.f;
}
__device__ __forceinline__ float fast_tanh(float x) {
  // tanh(x) = 1 - 2/(exp2(x*2*log2e)+1); exact at +-inf, ~1e-6 abs error
  const float z = __builtin_amdgcn_exp2f(x * 2.8853900817779268f);
  return 1.f - 2.f * __builtin_amdgcn_rcpf(z + 1.f);
}

// fragment-order index for B operand of mfma_f32_16x16x32_bf16:
// [kstep][ntile][lane=quad*16+n15][j], element (k,n): quad=(k>>3)&3, j=k&7
__device__ __forceinline__ int frag_idx(int k, int n) {
  return ((((k >> 5) * 8 + (n >> 4)) * 64) + (((k >> 3) & 3) * 16) + (n & 15)) * 8 + (k & 7);
}

// async 16B global -> LDS (wave-uniform base + lane*16 pattern)
__device__ __forceinline__ void g2lds16(const void* g, void* l) {
  __builtin_amdgcn_global_load_lds(
      (const __attribute__((address_space(1))) unsigned*)g,
      (__attribute__((address_space(3))) unsigned*)l, 16, 0, 0);
}
// stage 32KB of pre-formatted weights (16384 shorts) with 512 threads
__device__ __forceinline__ void stage_weights(const short* __restrict__ src,
                                              short* WS, int tid) {
  #pragma unroll
  for (int r = 0; r < 4; ++r) {
    const int off = (r * 512 + tid) * 8;   // 8 shorts = 16B per issue
    g2lds16(src + off, WS + off);
  }
}

// ------------- kernel 0: format weights to bf16 fragment order (once) -------
__global__ __launch_bounds__(256) void prep_kernel(
    const float* __restrict__ Wcf, const float* __restrict__ Wdf,
    const float* __restrict__ Wfc, short* __restrict__ Wcf_f,
    short* __restrict__ Wdf_f, short* __restrict__ Wfc_f) {
  const int e = blockIdx.x * 256 + threadIdx.x;   // 16384 total
  const int k = e >> 7, n = e & 127;
  const int fi = frag_idx(k, n);
  Wcf_f[fi] = f2b(Wcf[k * N_HID + n]);
  Wfc_f[fi] = f2b(Wfc[k * N_EMB + n]);
  Wdf_f[fi] = (k < N_DIST) ? f2b(Wdf[k * N_HID + n]) : (short)0;
}

// ---------------- kernel 1: afh = atom_features @ W_cf + b_cf (MFMA) --------
__global__ __launch_bounds__(512) void afh_kernel(
    const float* __restrict__ af, const short* __restrict__ Wcf_f,
    const float* __restrict__ bcf, float* __restrict__ afh) {
  __shared__ short WS[128 * 128];
  const int tid = threadIdx.x;
  const int lane = tid & 63, w = tid >> 6;
  const int lane15 = lane & 15, quad = lane >> 4;
  const int a0 = blockIdx.x * 128;

  stage_weights(Wcf_f, WS, tid);

  f32x4 acc[8];
  #pragma unroll
  for (int nt = 0; nt < 8; ++nt) {
    const float b = bcf[nt * 16 + lane15];
    acc[nt] = (f32x4){b, b, b, b};
  }
  const int arow = min(a0 + w * 16 + lane15, N_ATOMS - 1);
  const float* __restrict__ p = af + (long)arow * N_EMB;
  __syncthreads();                                  // WS staged

  for (int ks = 0; ks < 4; ++ks) {
    const int k0 = ks * 32 + quad * 8;
    const float4 x = *(const float4*)(p + k0);
    const float4 y = *(const float4*)(p + k0 + 4);
    bf16x8 a;
    a[0] = f2b(x.x); a[1] = f2b(x.y); a[2] = f2b(x.z); a[3] = f2b(x.w);
    a[4] = f2b(y.x); a[5] = f2b(y.y); a[6] = f2b(y.z); a[7] = f2b(y.w);
    #pragma unroll
    for (int nt = 0; nt < 8; ++nt) {
      const bf16x8 b = *(const bf16x8*)&WS[((ks * 8 + nt) * 64 + lane) * 8];
      acc[nt] = __builtin_amdgcn_mfma_f32_16x16x32_bf16(a, b, acc[nt], 0, 0, 0);
    }
  }
  #pragma unroll
  for (int reg = 0; reg < 4; ++reg) {
    const int row = a0 + w * 16 + quad * 4 + reg;
    if (row < N_ATOMS) {
      #pragma unroll
      for (int nt = 0; nt < 8; ++nt)
        afh[(long)row * N_HID + nt * 16 + lane15] = acc[nt][reg];
    }
  }
}

// ---------------- kernel 2: persistent fused pair kernel --------------------
// Each block stages Wdf+Wfc ONCE (64KB) and processes 8 waves x 25 strips of
// 16 contiguous pairs. Zero barriers in the loop (HS is wave-local); explicit
// 1-strip-ahead register prefetch of dist row + afh gather; segment
// accumulator carries across strips (sorted mi) -> fewer atomic flushes.
struct Pref {
  float4 x[4];      // dist k-chunks (x[3] = tail cols 96..99 for quad 0)
  float4 y[3];
  float  g[4][8];   // afh[mj[row]] gather, rows quad*4+reg, cols nt*16+lane15
};

__device__ __forceinline__ void prefetch_strip(
    const float* __restrict__ dist, const int* __restrict__ mj,
    const float* __restrict__ afh, long p0, int lane15, int quad, Pref& P) {
  const float* __restrict__ drow = dist + (p0 + lane15) * (long)N_DIST;
  #pragma unroll
  for (int ks = 0; ks < 3; ++ks) {                  // k0+7 <= 95 < 100
    const int k0 = ks * 32 + quad * 8;
    P.x[ks] = *(const float4*)(drow + k0);
    P.y[ks] = *(const float4*)(drow + k0 + 4);
  }
  const float4 z = {0.f, 0.f, 0.f, 0.f};
  P.x[3] = (quad == 0) ? *(const float4*)(drow + 96) : z;   // k 96..99
  #pragma unroll
  for (int reg = 0; reg < 4; ++reg) {
    const long j = mj[p0 + quad * 4 + reg];         // uniform per 16 lanes
    const float* __restrict__ arow = afh + j * N_HID + lane15;
    #pragma unroll
    for (int nt = 0; nt < 8; ++nt) P.g[reg][nt] = arow[nt * 16];  // 64B coalesced
  }
}

__device__ __forceinline__ void compute_strip(
    const Pref& P, const short* WS, short* HSw, const float* bv,
    int lane, int lane15, int quad, const int* __restrict__ mi, long p0,
    int& cur, float& s0, float& s1, float* __restrict__ agg, int c0) {
  // build A fragments from prefetched dist
  bf16x8 afr[4];
  #pragma unroll
  for (int ks = 0; ks < 3; ++ks) {
    afr[ks][0] = f2b(P.x[ks].x); afr[ks][1] = f2b(P.x[ks].y);
    afr[ks][2] = f2b(P.x[ks].z); afr[ks][3] = f2b(P.x[ks].w);
    afr[ks][4] = f2b(P.y[ks].x); afr[ks][5] = f2b(P.y[ks].y);
    afr[ks][6] = f2b(P.y[ks].z); afr[ks][7] = f2b(P.y[ks].w);
  }
  afr[3][0] = f2b(P.x[3].x); afr[3][1] = f2b(P.x[3].y);
  afr[3][2] = f2b(P.x[3].z); afr[3][3] = f2b(P.x[3].w);
  afr[3][4] = 0; afr[3][5] = 0; afr[3][6] = 0; afr[3][7] = 0;

  // phase A: dh[16x128] = dist_strip @ Wdf + bdf
  f32x4 acc[8];
  #pragma unroll
  for (int nt = 0; nt < 8; ++nt)
    acc[nt] = (f32x4){bv[nt], bv[nt], bv[nt], bv[nt]};
  #pragma unroll
  for (int ks = 0; ks < 4; ++ks) {
    #pragma unroll
    for (int nt = 0; nt < 8; ++nt) {
      const bf16x8 b = *(const bf16x8*)&WS[((ks * 8 + nt) * 64 + lane) * 8];
      acc[nt] = __builtin_amdgcn_mfma_f32_16x16x32_bf16(afr[ks], b, acc[nt], 0, 0, 0);
    }
  }

  // phase B: h = dh * afh_gather -> HSw (wave-local 16 rows, xor-swizzled)
  #pragma unroll
  for (int reg = 0; reg < 4; ++reg) {
    const int r = quad * 4 + reg;                   // local row 0..15
    #pragma unroll
    for (int nt = 0; nt < 8; ++nt) {
      const int col = nt * 16 + lane15;
      const float h = acc[nt][reg] * P.g[reg][nt];
      const int ch = (col >> 3) ^ r;
      HSw[(r << 7) + (ch << 3) + (col & 7)] = f2b(h);
    }
  }
  __builtin_amdgcn_wave_barrier();                  // same-wave DS in-order

  // phase C: msg[16x128] = h @ Wfc  (Wfc at WS+16384)
  f32x4 acc2[8];
  #pragma unroll
  for (int nt = 0; nt < 8; ++nt) acc2[nt] = (f32x4){0.f, 0.f, 0.f, 0.f};
  #pragma unroll
  for (int ks = 0; ks < 4; ++ks) {
    const int ch = (ks * 4 + quad) ^ lane15;        // local A-row = lane15
    const bf16x8 a = *(const bf16x8*)&HSw[(lane15 << 7) + (ch << 3)];
    #pragma unroll
    for (int nt = 0; nt < 8; ++nt) {
      const bf16x8 b = *(const bf16x8*)&WS[16384 + ((ks * 8 + nt) * 64 + lane) * 8];
      acc2[nt] = __builtin_amdgcn_mfma_f32_16x16x32_bf16(a, b, acc2[nt], 0, 0, 0);
    }
  }

  // epilogue: tanh -> HSw as msg (own rows only)
  #pragma unroll
  for (int reg = 0; reg < 4; ++reg) {
    const int r = quad * 4 + reg;
    #pragma unroll
    for (int nt = 0; nt < 8; ++nt) {
      const int col = nt * 16 + lane15;
      const float tv = fast_tanh(acc2[nt][reg]);
      const int ch = (col >> 3) ^ r;
      HSw[(r << 7) + (ch << 3) + (col & 7)] = f2b(tv);
    }
  }
  __builtin_amdgcn_wave_barrier();

  // segmented reduction over this strip's 16 sorted-mi rows (carry in/out)
  for (int rr = 0; rr < 16; ++rr) {
    const int idx = mi[p0 + rr];                    // wave-uniform value
    if (idx != cur) {                               // uniform branch at runtime
      atomicAdd(&agg[(size_t)cur * N_EMB + c0], s0);
      atomicAdd(&agg[(size_t)cur * N_EMB + c0 + 1], s1);
      s0 = s1 = 0.f; cur = idx;
    }
    const int ch = (c0 >> 3) ^ rr;                  // c0,c0+1 share chunk
    const unsigned v =
        *(const unsigned*)&HSw[(rr << 7) + (ch << 3) + (c0 & 7)];  // 2-way, free
    s0 += b2f((short)(v & 0xFFFF));
    s1 += b2f((short)(v >> 16));
  }
}

__global__ __launch_bounds__(512, 2) void pair_kernel(
    const float* __restrict__ dist, const int* __restrict__ mi,
    const int* __restrict__ mj, const short* __restrict__ Wdf_f,
    const short* __restrict__ Wfc_f, const float* __restrict__ bdf,
    const float* __restrict__ afh, float* __restrict__ agg) {
  __shared__ short WS[2 * 128 * 128];   // 64KB: Wdf then Wfc, frag order
  __shared__ short HS[8 * 16 * 128];    // 32KB: per-wave 16x128 h/msg tiles

  const int tid = threadIdx.x;
  const int lane = tid & 63;
  const int w = tid >> 6;
  const int lane15 = lane & 15;
  const int quad = lane >> 4;

  stage_weights(Wdf_f, WS, tid);                    // async, once per block
  stage_weights(Wfc_f, WS + 16384, tid);

  float bv[8];
  #pragma unroll
  for (int nt = 0; nt < 8; ++nt) bv[nt] = bdf[nt * 16 + lane15];

  short* HSw = HS + w * 2048;                       // wave-private 4KB
  const long wbase = ((long)blockIdx.x * 8 + w) * (SPW * 16);
  const int c0 = lane * 2;
  __syncthreads();                                  // weights staged (only barrier)

  Pref pa, pb;
  prefetch_strip(dist, mj, afh, wbase, lane15, quad, pa);
  int cur = mi[wbase];
  float s0 = 0.f, s1 = 0.f;

  #pragma unroll 1
  for (int s = 0; s < SPW - 1; s += 2) {
    prefetch_strip(dist, mj, afh, wbase + (s + 1) * 16, lane15, quad, pb);
    compute_strip(pa, WS, HSw, bv, lane, lane15, quad, mi, wbase + s * 16,
                  cur, s0, s1, agg, c0);
    prefetch_strip(dist, mj, afh, wbase + (s + 2) * 16, lane15, quad, pa);
    compute_strip(pb, WS, HSw, bv, lane, lane15, quad, mi, wbase + (s + 1) * 16,
                  cur, s0, s1, agg, c0);
  }
  compute_strip(pa, WS, HSw, bv, lane, lane15, quad, mi, wbase + (SPW - 1) * 16,
                cur, s0, s1, agg, c0);
  atomicAdd(&agg[(size_t)cur * N_EMB + c0], s0);
  atomicAdd(&agg[(size_t)cur * N_EMB + c0 + 1], s1);
}

// --- kernel 3: out = agg - tanh((b_df*afh) @ W_fc) + atom_features (MFMA) ---
__global__ __launch_bounds__(512) void out_kernel(
    const float* __restrict__ af, const float* __restrict__ afh,
    const short* __restrict__ Wfc_f, const float* __restrict__ bdf,
    const float* __restrict__ agg, float* __restrict__ out) {
  __shared__ short WS[128 * 128];
  const int tid = threadIdx.x;
  const int lane = tid & 63, w = tid >> 6;
  const int lane15 = lane & 15, quad = lane >> 4;
  const int a0 = blockIdx.x * 128;

  stage_weights(Wfc_f, WS, tid);

  f32x4 acc[8];
  #pragma unroll
  for (int nt = 0; nt < 8; ++nt) acc[nt] = (f32x4){0.f, 0.f, 0.f, 0.f};
  const int arow = min(a0 + w * 16 + lane15, N_ATOMS - 1);
  const float* __restrict__ p = afh + (long)arow * N_HID;
  __syncthreads();                                  // WS staged

  for (int ks = 0; ks < 4; ++ks) {
    const int k0 = ks * 32 + quad * 8;
    const float4 x = *(const float4*)(p + k0);
    const float4 y = *(const float4*)(p + k0 + 4);
    const float4 bx = *(const float4*)(bdf + k0);
    const float4 by = *(const float4*)(bdf + k0 + 4);
    bf16x8 a;
    a[0] = f2b(x.x * bx.x); a[1] = f2b(x.y * bx.y);
    a[2] = f2b(x.z * bx.z); a[3] = f2b(x.w * bx.w);
    a[4] = f2b(y.x * by.x); a[5] = f2b(y.y * by.y);
    a[6] = f2b(y.z * by.z); a[7] = f2b(y.w * by.w);
    #pragma unroll
    for (int nt = 0; nt < 8; ++nt) {
      const bf16x8 b = *(const bf16x8*)&WS[((ks * 8 + nt) * 64 + lane) * 8];
      acc[nt] = __builtin_amdgcn_mfma_f32_16x16x32_bf16(a, b, acc[nt], 0, 0, 0);
    }
  }
  #pragma unroll
  for (int reg = 0; reg < 4; ++reg) {
    const int row = a0 + w * 16 + quad * 4 + reg;
    if (row < N_ATOMS) {
      #pragma unroll
      for (int nt = 0; nt < 8; ++nt) {
        const size_t idx = (size_t)row * N_EMB + nt * 16 + lane15;
        out[idx] = agg[idx] - fast_tanh(acc[nt][reg]) + af[idx];
      }
    }
  }
}

extern "C" void kernel_launch(void* const* d_in, const int* in_sizes, int n_in,
                              void* d_out, int out_size, void* d_ws, size_t ws_size,
                              hipStream_t stream) {
  const float* af   = (const float*)d_in[0];
  const float* dist = (const float*)d_in[1];
  const int*   mi   = (const int*)d_in[3];
  const int*   mj   = (const int*)d_in[4];
  const float* Wcf  = (const float*)d_in[5];
  const float* Wdf  = (const float*)d_in[6];
  const float* Wfc  = (const float*)d_in[7];
  const float* bcf  = (const float*)d_in[8];
  const float* bdf  = (const float*)d_in[9];
  float* out = (float*)d_out;

  float* afh = (float*)d_ws;                        // 25.6 MB
  float* agg = afh + (size_t)N_ATOMS * N_HID;       // 25.6 MB
  short* Wcf_f = (short*)(agg + (size_t)N_ATOMS * N_EMB);  // 3 x 32KB, frag order
  short* Wdf_f = Wcf_f + 128 * 128;
  short* Wfc_f = Wdf_f + 128 * 128;

  hipMemsetAsync(agg, 0, (size_t)N_ATOMS * N_EMB * sizeof(float), stream);
  prep_kernel<<<64, 256, 0, stream>>>(Wcf, Wdf, Wfc, Wcf_f, Wdf_f, Wfc_f);
  afh_kernel<<<(N_ATOMS + 127) / 128, 512, 0, stream>>>(af, Wcf_f, bcf, afh);
  pair_kernel<<<NB, 512, 0, stream>>>(dist, mi, mj, Wdf_f, Wfc_f, bdf, afh, agg);
  out_kernel<<<(N_ATOMS + 127) / 128, 512, 0, stream>>>(af, afh, Wfc_f, bdf, agg, out);
}